// Round 15
// baseline (161.471 us; speedup 1.0000x reference)
//
#include <hip/hip_runtime.h>
#include <hip/hip_bf16.h>
#include <cmath>

#define N_NODES 2000
#define BS 8

typedef __attribute__((ext_vector_type(8))) short short8v;
typedef __attribute__((ext_vector_type(4))) float float4v;

__device__ __forceinline__ float elu_f(float v) { return v > 0.f ? v : expm1f(v); }

__device__ __forceinline__ unsigned short f32_bf16u(float f) {
    __hip_bfloat16 h = __float2bfloat16(f);
    unsigned short u;
    __builtin_memcpy(&u, &h, 2);
    return u;
}
__device__ __forceinline__ short f32_bf16(float f) { return (short)f32_bf16u(f); }

// pack two f32 -> one u32 of 2 bf16 (src0 -> lo, src1 -> hi)
__device__ __forceinline__ unsigned cvt_pk_bf16(float lo, float hi) {
    unsigned r;
    asm("v_cvt_pk_bf16_f32 %0, %1, %2" : "=v"(r) : "v"(lo), "v"(hi));
    return r;
}

// order-preserving f32 <-> u32 (for deterministic atomicMax on floats)
__device__ __forceinline__ unsigned f2ord(float f) {
    unsigned b = __float_as_uint(f);
    return (b & 0x80000000u) ? ~b : (b | 0x80000000u);
}
__device__ __forceinline__ float ord2f(unsigned u) {
    unsigned b = (u & 0x80000000u) ? (u & 0x7FFFFFFFu) : ~u;
    return __uint_as_float(b);
}

// ---- pack: adj bitmask + hT pad zero + md2u zero + bf16 x + layer1 P/Q/md ----
__global__ __launch_bounds__(256) void pack_kernel(
    const float* __restrict__ adj, const float* __restrict__ x,
    const float* __restrict__ W1, const float* __restrict__ a1,
    unsigned* __restrict__ maskT32, short* __restrict__ hT,
    short* __restrict__ xb16,
    float* __restrict__ PQ1, float* __restrict__ md1,
    unsigned* __restrict__ md2u) {
    __shared__ float2 redmm[256];
    int bx = blockIdx.x;
    int tid = threadIdx.x;
    if (bx < N_NODES) {
        int row = bx;
        int lane = tid & 63, wv = tid >> 6;
        for (int wq = wv; wq < 32; wq += 4) {
            int j = wq * 64 + lane;
            bool on = (j < N_NODES) && (adj[(size_t)row * N_NODES + j] > 0.f);
            unsigned long long bal = __ballot(on);
            if (lane == 0) {
                maskT32[(size_t)(2 * wq) * 2048 + row] = (unsigned)bal;
                maskT32[(size_t)(2 * wq + 1) * 2048 + row] = (unsigned)(bal >> 32);
            }
        }
        return;
    }
    if (bx == N_NODES) {
        for (int i = tid; i < 24 * 16 * 48; i += 256) {
            int bh = i / 768, rem = i % 768, f = rem / 48, n = N_NODES + rem % 48;
            hT[((size_t)bh * 16 + f) * 2048 + n] = 0;
        }
        if (tid < 24) md2u[tid] = 0u;   // encodes "most negative"
        return;
    }
    if (bx == N_NODES + 1) {
        for (int i = tid; i < BS * 2048; i += 256) {
            int b = i >> 11, n = i & 2047;
            xb16[i] = (n < N_NODES) ? f32_bf16(x[(size_t)b * N_NODES + n]) : 0;
        }
        return;
    }
    // layer1 prep: one block per bh (analytic colmax: d1 = wd*x)
    int bh = bx - (N_NODES + 2);   // 0..31
    int b = bh >> 2, h = bh & 3;
    float ws = 0.f, wd = 0.f;
    #pragma unroll
    for (int f = 0; f < 8; ++f) {
        float wv = W1[h * 8 + f];
        ws = fmaf(wv, a1[h * 16 + f], ws);
        wd = fmaf(wv, a1[h * 16 + 8 + f], wd);
    }
    float mn = 1e30f, mx = -1e30f;
    for (int n = tid; n < N_NODES; n += 256) {
        float v = x[(size_t)b * N_NODES + n];
        mn = fminf(mn, v); mx = fmaxf(mx, v);
    }
    redmm[tid] = make_float2(mn, mx);
    __syncthreads();
    for (int s = 128; s > 0; s >>= 1) {
        if (tid < s) {
            redmm[tid].x = fminf(redmm[tid].x, redmm[tid + s].x);
            redmm[tid].y = fmaxf(redmm[tid].y, redmm[tid + s].y);
        }
        __syncthreads();
    }
    float md = wd >= 0.f ? wd * redmm[0].y : wd * redmm[0].x;
    if (tid == 0) md1[bh] = md;
    float2* pq = (float2*)PQ1 + (size_t)bh * 2048;
    for (int n = tid; n < 2048; n += 256) {
        if (n < N_NODES) {
            float d = wd * x[(size_t)b * N_NODES + n] - md;
            pq[n] = make_float2(__expf(d), __expf(0.2f * d));
        } else {
            pq[n] = make_float2(0.f, 0.f);
        }
    }
}

// ---------------- att1: MFMA, B = [x, 1, 0...], K-halves, staged precomputed P/Q ----
// grid (32, 4, BS*2): z = b*2 + half. Shared md -> partials merge by addition.
__global__ __launch_bounds__(256) void att1_kernel(
    const unsigned* __restrict__ maskT32,
    const float* __restrict__ x, const short* __restrict__ xb16,
    const float* __restrict__ PQ1, const float* __restrict__ md1,
    const float* __restrict__ W1, const float* __restrict__ a1,
    float* __restrict__ pn1, float* __restrict__ pd1) {
    __shared__ float2 sPQ[1024];
    int tid = threadIdx.x;
    int head = blockIdx.y;
    int half = blockIdx.z & 1, b = blockIdx.z >> 1;
    int bh = b * 4 + head;
    int j0g = half * 1024;

    const float2* pq = (const float2*)PQ1 + (size_t)bh * 2048 + j0g;
    for (int i = tid; i < 1024; i += 256) sPQ[i] = pq[i];

    float ws = 0.f;
    #pragma unroll
    for (int f = 0; f < 8; ++f)
        ws = fmaf(W1[head * 8 + f], a1[head * 16 + f], ws);
    float md = md1[bh];
    __syncthreads();

    int lane = tid & 63;
    int wave = __builtin_amdgcn_readfirstlane(tid >> 6);
    int t = blockIdx.x * 4 + wave;
    if (t >= 125) return;
    int rs = lane & 15;      // C col: 0=num, 1=den
    int g = lane >> 4;
    int row = t * 16 + rs;

    float xr = x[(size_t)b * N_NODES + row];
    float u = ws * xr + md;
    float c = __expf(-0.8f * u);   // per-row scale cancels in final ratio

    unsigned fill = (rs == 1) ? 0x3F803F80u : 0u;
    bool isx = (rs == 0);
    const short* xbp = xb16 + (size_t)b * 2048 + j0g;

    float4v acc = {0.f, 0.f, 0.f, 0.f};

    for (int jcl = 0; jcl < 32; ++jcl) {
        int jb = jcl * 32 + g * 8;
        float4 pqa0 = *(const float4*)(&sPQ[jb]);
        float4 pqa1 = *(const float4*)(&sPQ[jb + 2]);
        float4 pqa2 = *(const float4*)(&sPQ[jb + 4]);
        float4 pqa3 = *(const float4*)(&sPQ[jb + 6]);
        float w[8];
        w[0] = fmaxf(pqa0.x, c * pqa0.y); w[1] = fmaxf(pqa0.z, c * pqa0.w);
        w[2] = fmaxf(pqa1.x, c * pqa1.y); w[3] = fmaxf(pqa1.z, c * pqa1.w);
        w[4] = fmaxf(pqa2.x, c * pqa2.y); w[5] = fmaxf(pqa2.z, c * pqa2.w);
        w[6] = fmaxf(pqa3.x, c * pqa3.y); w[7] = fmaxf(pqa3.z, c * pqa3.w);
        unsigned mby = maskT32[(size_t)(half * 32 + jcl) * 2048 + row] >> (g * 8);
        #pragma unroll
        for (int e = 0; e < 8; ++e)
            w[e] = (mby & (1u << e)) ? w[e] : 0.f;
        uint4 au;
        au.x = cvt_pk_bf16(w[0], w[1]);
        au.y = cvt_pk_bf16(w[2], w[3]);
        au.z = cvt_pk_bf16(w[4], w[5]);
        au.w = cvt_pk_bf16(w[6], w[7]);
        short8v av;
        __builtin_memcpy(&av, &au, 16);
        uint4 bu;
        if (isx) bu = *(const uint4*)(xbp + jb);
        else bu = make_uint4(fill, fill, fill, fill);
        short8v bv;
        __builtin_memcpy(&bv, &bu, 16);
        acc = __builtin_amdgcn_mfma_f32_16x16x32_bf16(av, bv, acc, 0, 0, 0);
    }

    #pragma unroll
    for (int reg = 0; reg < 4; ++reg) {
        int crow = t * 16 + g * 4 + reg;
        if (rs == 0) pn1[(size_t)(half * 32 + bh) * N_NODES + crow] = acc[reg];
        if (rs == 1) pd1[(size_t)(half * 32 + bh) * N_NODES + crow] = acc[reg];
    }
}

// ---- prep2: per (b,n) thread — merge att1 halves -> o1; h2/s2/d2; atomicMax md2 ----
__global__ __launch_bounds__(256) void prep2_kernel(
    const float* __restrict__ pn1, const float* __restrict__ pd1,
    const float* __restrict__ W1,
    const float* __restrict__ W2, const float* __restrict__ a2,
    float* __restrict__ o1, short* __restrict__ hT,
    float* __restrict__ s2, float* __restrict__ d2,
    unsigned* __restrict__ md2u) {
    __shared__ float sW[1536];
    int tid = threadIdx.x;
    for (int i = tid; i < 1536; i += 256) sW[i] = W2[i];
    __syncthreads();
    int idx = blockIdx.x * 256 + tid;
    bool act = idx < BS * N_NODES;
    int b = act ? idx / N_NODES : 0;
    int n = act ? idx % N_NODES : 0;

    float o1f[32];
    if (act) {
        #pragma unroll
        for (int head = 0; head < 4; ++head) {
            int bh = b * 4 + head;
            float num = pn1[(size_t)bh * N_NODES + n]
                      + pn1[(size_t)(32 + bh) * N_NODES + n];
            float den = pd1[(size_t)bh * N_NODES + n]
                      + pd1[(size_t)(32 + bh) * N_NODES + n];
            float ratio = den > 0.f ? num / den : 0.f;
            #pragma unroll
            for (int f = 0; f < 8; ++f) {
                float v = ratio * W1[head * 8 + f];
                o1f[head * 8 + f] = v > 0.f ? v : expm1f(v);
            }
        }
        float4* op = (float4*)(o1 + (size_t)idx * 32);
        #pragma unroll
        for (int q = 0; q < 8; ++q)
            op[q] = make_float4(o1f[4 * q], o1f[4 * q + 1], o1f[4 * q + 2], o1f[4 * q + 3]);
    }

    float dmax[3];
    #pragma unroll
    for (int h = 0; h < 3; ++h) {
        dmax[h] = -1e30f;
        if (act) {
            int bh = b * 3 + h;
            float hv[16];
            #pragma unroll
            for (int f = 0; f < 16; ++f) hv[f] = 0.f;
            #pragma unroll
            for (int k = 0; k < 32; ++k) {
                float ik = o1f[k];
                #pragma unroll
                for (int f = 0; f < 16; ++f) hv[f] = fmaf(ik, sW[h * 512 + k * 16 + f], hv[f]);
            }
            float sr = 0.f, ds = 0.f;
            #pragma unroll
            for (int f = 0; f < 16; ++f) {
                hT[((size_t)bh * 16 + f) * 2048 + n] = f32_bf16(hv[f]);
                sr = fmaf(hv[f], a2[h * 32 + f], sr);
                ds = fmaf(hv[f], a2[h * 32 + 16 + f], ds);
            }
            s2[(size_t)bh * N_NODES + n] = sr;
            d2[(size_t)bh * N_NODES + n] = ds;
            dmax[h] = ds;
        }
    }
    // wave-reduced deterministic atomicMax (max is order-independent)
    int lane = tid & 63;
    int b0 = __shfl(b, 0, 64);
    #pragma unroll
    for (int h = 0; h < 3; ++h) {
        float m = (act && b == b0) ? dmax[h] : -1e30f;
        #pragma unroll
        for (int off = 32; off >= 1; off >>= 1)
            m = fmaxf(m, __shfl_xor(m, off, 64));
        if (lane == 0 && act) atomicMax(&md2u[b0 * 3 + h], f2ord(m));
        if (act && b != b0) atomicMax(&md2u[b * 3 + h], f2ord(dmax[h]));
    }
}

// ---------------- att2: bf16 MFMA, K-halves, in-preamble P/Q from d2+md2 ----------
// grid (32, 3, BS*2)
__global__ __launch_bounds__(256) void att2_kernel(
    const unsigned* __restrict__ maskT32,
    const short* __restrict__ hT,
    const float* __restrict__ s2, const float* __restrict__ d2,
    const unsigned* __restrict__ md2u,
    float* __restrict__ pn2, float* __restrict__ pd2) {
    __shared__ float2 sPQ[1024];
    int tid = threadIdx.x;
    int head = blockIdx.y;
    int half = blockIdx.z & 1, b = blockIdx.z >> 1;
    int bh = b * 3 + head;
    int j0g = half * 1024;

    float md = ord2f(md2u[bh]);
    const float* dp = d2 + (size_t)bh * N_NODES;
    for (int i = tid; i < 1024; i += 256) {
        int j = j0g + i;
        if (j < N_NODES) {
            float d = dp[j] - md;
            sPQ[i] = make_float2(__expf(d), __expf(0.2f * d));
        } else {
            sPQ[i] = make_float2(0.f, 0.f);
        }
    }
    __syncthreads();

    int lane = tid & 63;
    int wave = __builtin_amdgcn_readfirstlane(tid >> 6);
    int t = blockIdx.x * 4 + wave;
    if (t >= 125) return;
    int rs = lane & 15;      // C col (feature)
    int g = lane >> 4;
    int row = t * 16 + rs;

    float sv = s2[(size_t)bh * N_NODES + row];
    float u = sv + md;
    float c = __expf(-0.8f * u);
    const short* hb = hT + ((size_t)bh * 16 + rs) * 2048 + j0g;

    const unsigned one2 = 0x3F803F80u;
    uint4 ou = make_uint4(one2, one2, one2, one2);
    short8v onesv;
    __builtin_memcpy(&onesv, &ou, 16);

    float4v acc = {0.f, 0.f, 0.f, 0.f};
    float4v accd = {0.f, 0.f, 0.f, 0.f};

    for (int jcl = 0; jcl < 32; ++jcl) {
        int jb = jcl * 32 + g * 8;
        float4 pqa0 = *(const float4*)(&sPQ[jb]);
        float4 pqa1 = *(const float4*)(&sPQ[jb + 2]);
        float4 pqa2 = *(const float4*)(&sPQ[jb + 4]);
        float4 pqa3 = *(const float4*)(&sPQ[jb + 6]);
        float w[8];
        w[0] = fmaxf(pqa0.x, c * pqa0.y); w[1] = fmaxf(pqa0.z, c * pqa0.w);
        w[2] = fmaxf(pqa1.x, c * pqa1.y); w[3] = fmaxf(pqa1.z, c * pqa1.w);
        w[4] = fmaxf(pqa2.x, c * pqa2.y); w[5] = fmaxf(pqa2.z, c * pqa2.w);
        w[6] = fmaxf(pqa3.x, c * pqa3.y); w[7] = fmaxf(pqa3.z, c * pqa3.w);
        unsigned mby = maskT32[(size_t)(half * 32 + jcl) * 2048 + row] >> (g * 8);
        #pragma unroll
        for (int e = 0; e < 8; ++e)
            w[e] = (mby & (1u << e)) ? w[e] : 0.f;
        uint4 au;
        au.x = cvt_pk_bf16(w[0], w[1]);
        au.y = cvt_pk_bf16(w[2], w[3]);
        au.z = cvt_pk_bf16(w[4], w[5]);
        au.w = cvt_pk_bf16(w[6], w[7]);
        short8v av;
        __builtin_memcpy(&av, &au, 16);
        short8v bv = *(const short8v*)(hb + jb);
        acc = __builtin_amdgcn_mfma_f32_16x16x32_bf16(av, bv, acc, 0, 0, 0);
        accd = __builtin_amdgcn_mfma_f32_16x16x32_bf16(av, onesv, accd, 0, 0, 0);
    }

    #pragma unroll
    for (int reg = 0; reg < 4; ++reg) {
        int crow = t * 16 + g * 4 + reg;
        pn2[((size_t)(half * 24 + bh) * N_NODES + crow) * 16 + rs] = acc[reg];
        if (rs == 0) pd2[(size_t)(half * 24 + bh) * N_NODES + crow] = accd[reg];
    }
}

// ---------------- finish2: sum halves -> o2 (shared md, plain add) ----------------
__global__ __launch_bounds__(256) void finish2_kernel(
    const float* __restrict__ pn2, const float* __restrict__ pd2,
    float* __restrict__ o2) {
    int idx = blockIdx.x * 256 + threadIdx.x;
    if (idx >= 24 * N_NODES) return;
    int bh = idx / N_NODES, n = idx % N_NODES;
    int b = bh / 3, h = bh % 3;
    float den = pd2[(size_t)bh * N_NODES + n] + pd2[(size_t)(24 + bh) * N_NODES + n];
    float inv = den > 0.f ? 1.0f / den : 0.f;
    const float4* pa = (const float4*)(pn2 + ((size_t)bh * N_NODES + n) * 16);
    const float4* pb = (const float4*)(pn2 + ((size_t)(24 + bh) * N_NODES + n) * 16);
    float* op = o2 + ((size_t)b * N_NODES + n) * 48 + h * 16;
    #pragma unroll
    for (int q = 0; q < 4; ++q) {
        float4 va = pa[q], vb = pb[q];
        float v0 = (va.x + vb.x) * inv;
        float v1 = (va.y + vb.y) * inv;
        float v2 = (va.z + vb.z) * inv;
        float v3 = (va.w + vb.w) * inv;
        op[4 * q + 0] = v0 > 0.f ? v0 : expm1f(v0);
        op[4 * q + 1] = v1 > 0.f ? v1 : expm1f(v1);
        op[4 * q + 2] = v2 > 0.f ? v2 : expm1f(v2);
        op[4 * q + 3] = v3 > 0.f ? v3 : expm1f(v3);
    }
}

// ---------------- fc1 split-K with inline concat/projection staging ----------------
__global__ __launch_bounds__(256) void fc1_splitk_kernel(
    const float* __restrict__ x,
    const float* __restrict__ o1, const float* __restrict__ o2,
    const float* __restrict__ pw1, const float* __restrict__ pb1,
    const float* __restrict__ pw2, const float* __restrict__ pb2,
    const float* __restrict__ W, float* __restrict__ partial) {
    const int K = 6000, O = 600, KS = 71;
    __shared__ float sz[BS][KS];
    int tid = threadIdx.x;
    int kt = blockIdx.y;
    int k0 = kt * KS;
    int len = (k0 + KS <= K) ? KS : (K - k0);
    float pb1v = pb1[0], pb2v = pb2[0];
    for (int i = tid; i < BS * len; i += 256) {
        int bb = i / len, k = k0 + i % len;
        float v;
        if (k < 2000) {
            v = x[bb * 2000 + k];
        } else if (k < 4000) {
            const float* op = o1 + ((size_t)bb * 2000 + (k - 2000)) * 32;
            float s = pb1v;
            #pragma unroll
            for (int q = 0; q < 32; ++q) s = fmaf(op[q], pw1[q], s);
            v = s;
        } else {
            const float* op = o2 + ((size_t)bb * 2000 + (k - 4000)) * 48;
            float s = pb2v;
            #pragma unroll
            for (int q = 0; q < 48; ++q) s = fmaf(op[q], pw2[q], s);
            v = s;
        }
        sz[bb][i % len] = v;
    }
    __syncthreads();
    int o = blockIdx.x * 256 + tid;
    float acc[BS] = {0.f, 0.f, 0.f, 0.f, 0.f, 0.f, 0.f, 0.f};
    if (o < O) {
        for (int k = 0; k < len; ++k) {
            float w = W[(size_t)(k0 + k) * O + o];
            #pragma unroll
            for (int b = 0; b < BS; ++b) acc[b] = fmaf(sz[b][k], w, acc[b]);
        }
        #pragma unroll
        for (int b = 0; b < BS; ++b)
            partial[((size_t)kt * BS + b) * O + o] = acc[b];
    }
}

// ---------------- fc2 split-K with inline fc1-reduce staging — grid (1, 16) ----------
__global__ __launch_bounds__(256) void fc2_splitk_kernel(
    const float* __restrict__ p1, const float* __restrict__ b1,
    const float* __restrict__ W, float* __restrict__ partial) {
    const int K = 600, O = 256, KS = 38;
    __shared__ float sz[BS][KS];
    int tid = threadIdx.x;
    int kt = blockIdx.y;
    int k0 = kt * KS;
    int k1 = k0 + KS < K ? k0 + KS : K;
    int len = k1 - k0;
    for (int i = tid; i < BS * len; i += 256) {
        int bb = i / len, k = k0 + i % len;
        float a = b1[k];
        #pragma unroll 5
        for (int q = 0; q < 85; ++q) a += p1[((size_t)q * BS + bb) * 600 + k];
        sz[bb][i % len] = elu_f(a);
    }
    __syncthreads();
    int o = tid;
    float acc[BS] = {0.f, 0.f, 0.f, 0.f, 0.f, 0.f, 0.f, 0.f};
    for (int k = 0; k < len; ++k) {
        float w = W[(size_t)(k0 + k) * O + o];
        #pragma unroll
        for (int b = 0; b < BS; ++b) acc[b] = fmaf(sz[b][k], w, acc[b]);
    }
    #pragma unroll
    for (int b = 0; b < BS; ++b)
        partial[((size_t)kt * BS + b) * O + o] = acc[b];
}

// ---------------- fc_tail: p2-reduce + fc3 + fc4 + fc5 — grid (BS) ----------------
__global__ __launch_bounds__(256) void fc_tail_kernel(
    const float* __restrict__ p2, const float* __restrict__ b2,
    const float* __restrict__ w3, const float* __restrict__ b3,
    const float* __restrict__ w4, const float* __restrict__ b4,
    const float* __restrict__ w5, const float* __restrict__ b5,
    float* __restrict__ outp) {
    int b = blockIdx.x, tid = threadIdx.x;
    __shared__ float t2[256], red[256], z1[64], z4[32];
    {
        float a = b2[tid];
        #pragma unroll
        for (int kt = 0; kt < 16; ++kt) a += p2[((size_t)kt * BS + b) * 256 + tid];
        t2[tid] = elu_f(a);
    }
    __syncthreads();
    {
        int o = tid & 63, ks = tid >> 6;
        float a = 0.f;
        for (int k = ks; k < 256; k += 4) a = fmaf(t2[k], w3[k * 64 + o], a);
        red[tid] = a;
        __syncthreads();
        if (ks == 0) {
            float v = red[o] + red[64 + o] + red[128 + o] + red[192 + o] + b3[o];
            v = elu_f(v);
            z1[o] = v;
            outp[b * 64 + o] = v;
        }
    }
    __syncthreads();
    if (tid < 32) {
        float v = b4[tid];
        #pragma unroll
        for (int k = 0; k < 64; ++k) v = fmaf(z1[k], w4[k * 32 + tid], v);
        z4[tid] = elu_f(v);
    }
    __syncthreads();
    if (tid < 2) {
        float v = b5[tid];
        #pragma unroll
        for (int k = 0; k < 32; ++k) v = fmaf(z4[k], w5[k * 2 + tid], v);
        outp[BS * 64 + b * 2 + tid] = v;
    }
}

extern "C" void kernel_launch(void* const* d_in, const int* in_sizes, int n_in,
                              void* d_out, int out_size, void* d_ws, size_t ws_size,
                              hipStream_t stream) {
    const float* x    = (const float*)d_in[0];
    const float* adj  = (const float*)d_in[1];
    const float* W1   = (const float*)d_in[2];
    const float* a1   = (const float*)d_in[3];
    const float* W2   = (const float*)d_in[4];
    const float* a2   = (const float*)d_in[5];
    const float* pw1  = (const float*)d_in[6];
    const float* pb1  = (const float*)d_in[7];
    const float* pw2  = (const float*)d_in[8];
    const float* pb2  = (const float*)d_in[9];
    const float* fc1w = (const float*)d_in[10];
    const float* fc1b = (const float*)d_in[11];
    const float* fc2w = (const float*)d_in[12];
    const float* fc2b = (const float*)d_in[13];
    const float* fc3w = (const float*)d_in[14];
    const float* fc3b = (const float*)d_in[15];
    const float* fc4w = (const float*)d_in[16];
    const float* fc4b = (const float*)d_in[17];
    const float* fc5w = (const float*)d_in[18];
    const float* fc5b = (const float*)d_in[19];
    float* outp = (float*)d_out;

    float* ws = (float*)d_ws;
    size_t off = 0;
    auto alloc = [&](size_t n) {
        float* p = ws + off;
        off += (n + 63) & ~(size_t)63;
        return p;
    };
    float* o1   = alloc((size_t)BS * N_NODES * 32);
    float* s2   = alloc((size_t)24 * N_NODES);
    float* d2   = alloc((size_t)24 * N_NODES);
    short* hT   = (short*)alloc((size_t)24 * 16 * 2048 / 2);
    short* xb16 = (short*)alloc((size_t)BS * 2048 / 2);
    float* o2   = alloc((size_t)BS * N_NODES * 48);
    const int KT1 = 85;
    float* p1   = alloc((size_t)KT1 * BS * 600);
    float* p2   = alloc((size_t)16 * BS * 256);
    float* pn1  = alloc((size_t)2 * 32 * N_NODES);
    float* pd1  = alloc((size_t)2 * 32 * N_NODES);
    float* PQ1  = alloc((size_t)32 * 4096);
    float* md1  = alloc(64);
    float* pn2  = alloc((size_t)2 * 24 * N_NODES * 16);
    float* pd2  = alloc((size_t)2 * 24 * N_NODES);
    unsigned* md2u = (unsigned*)alloc(64);
    unsigned* maskT32 = (unsigned*)alloc((size_t)64 * 2048);

    pack_kernel<<<N_NODES + 2 + 32, 256, 0, stream>>>(
        adj, x, W1, a1, maskT32, hT, xb16, PQ1, md1, md2u);
    att1_kernel<<<dim3(32, 4, BS * 2), 256, 0, stream>>>(
        maskT32, x, xb16, PQ1, md1, W1, a1, pn1, pd1);
    prep2_kernel<<<(BS * N_NODES + 255) / 256, 256, 0, stream>>>(
        pn1, pd1, W1, W2, a2, o1, hT, s2, d2, md2u);
    att2_kernel<<<dim3(32, 3, BS * 2), 256, 0, stream>>>(
        maskT32, hT, s2, d2, md2u, pn2, pd2);
    finish2_kernel<<<(24 * N_NODES + 255) / 256, 256, 0, stream>>>(pn2, pd2, o2);
    fc1_splitk_kernel<<<dim3(3, KT1), 256, 0, stream>>>(
        x, o1, o2, pw1, pb1, pw2, pb2, fc1w, p1);
    fc2_splitk_kernel<<<dim3(1, 16), 256, 0, stream>>>(p1, fc1b, fc2w, p2);
    fc_tail_kernel<<<BS, 256, 0, stream>>>(
        p2, fc2b, fc3w, fc3b, fc4w, fc4b, fc5w, fc5b, outp);
}

// Round 16
// 138.062 us; speedup vs baseline: 1.1696x; 1.1696x over previous
//
#include <hip/hip_runtime.h>
#include <hip/hip_bf16.h>
#include <cmath>

#define N_NODES 2000
#define BS 8

typedef __attribute__((ext_vector_type(8))) short short8v;
typedef __attribute__((ext_vector_type(4))) float float4v;

__device__ __forceinline__ float elu_f(float v) { return v > 0.f ? v : expm1f(v); }

__device__ __forceinline__ unsigned short f32_bf16u(float f) {
    __hip_bfloat16 h = __float2bfloat16(f);
    unsigned short u;
    __builtin_memcpy(&u, &h, 2);
    return u;
}
__device__ __forceinline__ short f32_bf16(float f) { return (short)f32_bf16u(f); }

// pack two f32 -> one u32 of 2 bf16 (src0 -> lo, src1 -> hi)
__device__ __forceinline__ unsigned cvt_pk_bf16(float lo, float hi) {
    unsigned r;
    asm("v_cvt_pk_bf16_f32 %0, %1, %2" : "=v"(r) : "v"(lo), "v"(hi));
    return r;
}

// ---- pack: adj bitmask + hT pad zero + bf16 x + layer1 P/Q/md (analytic colmax) ----
__global__ __launch_bounds__(256) void pack_kernel(
    const float* __restrict__ adj, const float* __restrict__ x,
    const float* __restrict__ W1, const float* __restrict__ a1,
    unsigned* __restrict__ maskT32, short* __restrict__ hT,
    short* __restrict__ xb16,
    float* __restrict__ PQ1, float* __restrict__ md1) {
    __shared__ float2 redmm[256];
    int bx = blockIdx.x;
    int tid = threadIdx.x;
    if (bx < N_NODES) {
        int row = bx;
        int lane = tid & 63, wv = tid >> 6;
        for (int wq = wv; wq < 32; wq += 4) {
            int j = wq * 64 + lane;
            bool on = (j < N_NODES) && (adj[(size_t)row * N_NODES + j] > 0.f);
            unsigned long long bal = __ballot(on);
            if (lane == 0) {
                maskT32[(size_t)(2 * wq) * 2048 + row] = (unsigned)bal;
                maskT32[(size_t)(2 * wq + 1) * 2048 + row] = (unsigned)(bal >> 32);
            }
        }
        return;
    }
    if (bx == N_NODES) {
        for (int i = tid; i < 24 * 16 * 48; i += 256) {
            int bh = i / 768, rem = i % 768, f = rem / 48, n = N_NODES + rem % 48;
            hT[((size_t)bh * 16 + f) * 2048 + n] = 0;
        }
        return;
    }
    if (bx == N_NODES + 1) {
        for (int i = tid; i < BS * 2048; i += 256) {
            int b = i >> 11, n = i & 2047;
            xb16[i] = (n < N_NODES) ? f32_bf16(x[(size_t)b * N_NODES + n]) : 0;
        }
        return;
    }
    // layer1 prep: one block per bh (analytic colmax: d1 = wd*x)
    int bh = bx - (N_NODES + 2);   // 0..31
    int b = bh >> 2, h = bh & 3;
    float ws = 0.f, wd = 0.f;
    #pragma unroll
    for (int f = 0; f < 8; ++f) {
        float wv = W1[h * 8 + f];
        ws = fmaf(wv, a1[h * 16 + f], ws);
        wd = fmaf(wv, a1[h * 16 + 8 + f], wd);
    }
    float mn = 1e30f, mx = -1e30f;
    for (int n = tid; n < N_NODES; n += 256) {
        float v = x[(size_t)b * N_NODES + n];
        mn = fminf(mn, v); mx = fmaxf(mx, v);
    }
    redmm[tid] = make_float2(mn, mx);
    __syncthreads();
    for (int s = 128; s > 0; s >>= 1) {
        if (tid < s) {
            redmm[tid].x = fminf(redmm[tid].x, redmm[tid + s].x);
            redmm[tid].y = fmaxf(redmm[tid].y, redmm[tid + s].y);
        }
        __syncthreads();
    }
    float md = wd >= 0.f ? wd * redmm[0].y : wd * redmm[0].x;
    if (tid == 0) md1[bh] = md;
    float2* pq = (float2*)PQ1 + (size_t)bh * 2048;
    for (int n = tid; n < 2048; n += 256) {
        if (n < N_NODES) {
            float d = wd * x[(size_t)b * N_NODES + n] - md;
            pq[n] = make_float2(__expf(d), __expf(0.2f * d));
        } else {
            pq[n] = make_float2(0.f, 0.f);
        }
    }
}

// ---------------- att1: MFMA, B = [x, 1, 0...], staged precomputed P/Q + LDS x ------
// grid (32, 4, BS) — R11-proven inner loop verbatim.
__global__ __launch_bounds__(256) void att1_kernel(
    const unsigned* __restrict__ maskT32,
    const float* __restrict__ x, const short* __restrict__ xb16,
    const float* __restrict__ PQ1, const float* __restrict__ md1,
    const float* __restrict__ W1, const float* __restrict__ a1,
    float* __restrict__ o1) {
    __shared__ float2 sPQ[2048];
    __shared__ short sXb[2048];
    int tid = threadIdx.x;
    int head = blockIdx.y, b = blockIdx.z;
    int bh = b * 4 + head;

    const float2* pq = (const float2*)PQ1 + (size_t)bh * 2048;
    const short* xbp = xb16 + (size_t)b * 2048;
    for (int i = tid; i < 2048; i += 256) {
        sPQ[i] = pq[i];
        sXb[i] = xbp[i];
    }
    float ws = 0.f;
    #pragma unroll
    for (int f = 0; f < 8; ++f)
        ws = fmaf(W1[head * 8 + f], a1[head * 16 + f], ws);
    float md = md1[bh];
    __syncthreads();

    int lane = tid & 63;
    int wave = __builtin_amdgcn_readfirstlane(tid >> 6);
    int t = blockIdx.x * 4 + wave;
    if (t >= 125) return;
    int rs = lane & 15;      // C col: 0=num, 1=den
    int g = lane >> 4;
    int row = t * 16 + rs;

    float xr = x[(size_t)b * N_NODES + row];
    float u = ws * xr + md;
    float c = __expf(-0.8f * u);   // B/A; A cancels in num/den

    unsigned fill = (rs == 1) ? 0x3F803F80u : 0u;  // bf16 1.0 pair
    bool isx = (rs == 0);

    float4v acc = {0.f, 0.f, 0.f, 0.f};

    for (int jc = 0; jc < 64; ++jc) {
        int jb = jc * 32 + g * 8;
        float4 pqa0 = *(const float4*)(&sPQ[jb]);
        float4 pqa1 = *(const float4*)(&sPQ[jb + 2]);
        float4 pqa2 = *(const float4*)(&sPQ[jb + 4]);
        float4 pqa3 = *(const float4*)(&sPQ[jb + 6]);
        float w[8];
        w[0] = fmaxf(pqa0.x, c * pqa0.y); w[1] = fmaxf(pqa0.z, c * pqa0.w);
        w[2] = fmaxf(pqa1.x, c * pqa1.y); w[3] = fmaxf(pqa1.z, c * pqa1.w);
        w[4] = fmaxf(pqa2.x, c * pqa2.y); w[5] = fmaxf(pqa2.z, c * pqa2.w);
        w[6] = fmaxf(pqa3.x, c * pqa3.y); w[7] = fmaxf(pqa3.z, c * pqa3.w);
        unsigned mby = maskT32[(size_t)jc * 2048 + row] >> (g * 8);
        #pragma unroll
        for (int e = 0; e < 8; ++e)
            w[e] = (mby & (1u << e)) ? w[e] : 0.f;
        uint4 au;
        au.x = cvt_pk_bf16(w[0], w[1]);
        au.y = cvt_pk_bf16(w[2], w[3]);
        au.z = cvt_pk_bf16(w[4], w[5]);
        au.w = cvt_pk_bf16(w[6], w[7]);
        short8v av;
        __builtin_memcpy(&av, &au, 16);
        uint4 bu;
        if (isx) bu = *(const uint4*)(sXb + jb);
        else bu = make_uint4(fill, fill, fill, fill);
        short8v bv;
        __builtin_memcpy(&bv, &bu, 16);
        acc = __builtin_amdgcn_mfma_f32_16x16x32_bf16(av, bv, acc, 0, 0, 0);
    }

    // readout: num at lane g*16+0, den at lane g*16+1 (C: col=lane&15, row=g*4+reg)
    #pragma unroll
    for (int reg = 0; reg < 4; ++reg) {
        int crow = g * 4 + reg;
        float nm = __shfl(acc[reg], lane & 48, 64);
        float dn = __shfl(acc[reg], (lane & 48) | 1, 64);
        float ratio = dn > 0.f ? nm / dn : 0.f;
        if (rs < 8) {
            float v = ratio * W1[head * 8 + rs];
            v = v > 0.f ? v : expm1f(v);
            o1[((size_t)(b * N_NODES + t * 16 + crow)) * 32 + head * 8 + rs] = v;
        }
    }
}

// ---------------- prep2: h2 = o1@W2 (bf16 hT [bh][f][2048]); s2/d2 (R11 verbatim) ----
__global__ __launch_bounds__(256) void prep2_kernel(
    const float* __restrict__ o1, const float* __restrict__ W2,
    const float* __restrict__ a2,
    short* __restrict__ hT, float* __restrict__ s2, float* __restrict__ d2) {
    __shared__ float sW[1536];
    int tid = threadIdx.x;
    for (int i = tid; i < 1536; i += 256) sW[i] = W2[i];
    __syncthreads();
    int idx = blockIdx.x * 256 + tid;
    if (idx >= BS * 3 * N_NODES) return;
    int b = idx / 6000, r = idx % 6000, h = r / N_NODES, n = r % N_NODES;
    int bh = b * 3 + h;
    float in[32];
    const float4* ip = (const float4*)(o1 + ((size_t)b * N_NODES + n) * 32);
    #pragma unroll
    for (int q = 0; q < 8; ++q) {
        float4 v = ip[q];
        in[4 * q] = v.x; in[4 * q + 1] = v.y; in[4 * q + 2] = v.z; in[4 * q + 3] = v.w;
    }
    float hv[16];
    #pragma unroll
    for (int f = 0; f < 16; ++f) hv[f] = 0.f;
    #pragma unroll
    for (int k = 0; k < 32; ++k) {
        float ik = in[k];
        #pragma unroll
        for (int f = 0; f < 16; ++f) hv[f] = fmaf(ik, sW[h * 512 + k * 16 + f], hv[f]);
    }
    float sr = 0.f, ds = 0.f;
    #pragma unroll
    for (int f = 0; f < 16; ++f) {
        hT[((size_t)bh * 16 + f) * 2048 + n] = f32_bf16(hv[f]);
        sr = fmaf(hv[f], a2[h * 32 + f], sr);
        ds = fmaf(hv[f], a2[h * 32 + 16 + f], ds);
    }
    s2[(size_t)bh * N_NODES + n] = sr;
    d2[(size_t)bh * N_NODES + n] = ds;
}

// ---------------- att2: bf16 MFMA, w' = max(P, c*Q), den via ones-MFMA (R11) --------
__global__ __launch_bounds__(256) void att2_kernel(
    const unsigned* __restrict__ maskT32,
    const short* __restrict__ hT,
    const float* __restrict__ s2, const float* __restrict__ d2,
    float* __restrict__ o2) {
    __shared__ float2 sPQ[2048];
    __shared__ float red[256];
    int tid = threadIdx.x;
    int head = blockIdx.y, b = blockIdx.z, bh = b * 3 + head;
    const float* dp = d2 + (size_t)bh * N_NODES;

    float mx = -1e30f;
    for (int n = tid; n < N_NODES; n += 256) mx = fmaxf(mx, dp[n]);
    red[tid] = mx;
    __syncthreads();
    for (int s = 128; s > 0; s >>= 1) {
        if (tid < s) red[tid] = fmaxf(red[tid], red[tid + s]);
        __syncthreads();
    }
    float md = red[0];
    for (int n = tid; n < 2048; n += 256) {
        if (n < N_NODES) {
            float d = dp[n] - md;
            sPQ[n] = make_float2(__expf(d), __expf(0.2f * d));
        } else {
            sPQ[n] = make_float2(0.f, 0.f);
        }
    }
    __syncthreads();

    int lane = tid & 63;
    int wave = __builtin_amdgcn_readfirstlane(tid >> 6);
    int t = blockIdx.x * 4 + wave;
    if (t >= 125) return;
    int rs = lane & 15;      // A row in tile == C col (feature)
    int g = lane >> 4;       // k-group
    int row = t * 16 + rs;

    float sv = s2[(size_t)bh * N_NODES + row];
    float u = sv + md;
    float c = __expf(-0.8f * u);
    const short* hb = hT + ((size_t)bh * 16 + rs) * 2048;

    const unsigned one2 = 0x3F803F80u;
    uint4 ou = make_uint4(one2, one2, one2, one2);
    short8v onesv;
    __builtin_memcpy(&onesv, &ou, 16);

    float4v acc = {0.f, 0.f, 0.f, 0.f};
    float4v accd = {0.f, 0.f, 0.f, 0.f};

    for (int jc = 0; jc < 64; ++jc) {
        int jb = jc * 32 + g * 8;
        float4 pqa0 = *(const float4*)(&sPQ[jb]);
        float4 pqa1 = *(const float4*)(&sPQ[jb + 2]);
        float4 pqa2 = *(const float4*)(&sPQ[jb + 4]);
        float4 pqa3 = *(const float4*)(&sPQ[jb + 6]);
        float w[8];
        w[0] = fmaxf(pqa0.x, c * pqa0.y); w[1] = fmaxf(pqa0.z, c * pqa0.w);
        w[2] = fmaxf(pqa1.x, c * pqa1.y); w[3] = fmaxf(pqa1.z, c * pqa1.w);
        w[4] = fmaxf(pqa2.x, c * pqa2.y); w[5] = fmaxf(pqa2.z, c * pqa2.w);
        w[6] = fmaxf(pqa3.x, c * pqa3.y); w[7] = fmaxf(pqa3.z, c * pqa3.w);
        unsigned mby = maskT32[(size_t)jc * 2048 + row] >> (g * 8);
        #pragma unroll
        for (int e = 0; e < 8; ++e)
            w[e] = (mby & (1u << e)) ? w[e] : 0.f;
        uint4 au;
        au.x = cvt_pk_bf16(w[0], w[1]);
        au.y = cvt_pk_bf16(w[2], w[3]);
        au.z = cvt_pk_bf16(w[4], w[5]);
        au.w = cvt_pk_bf16(w[6], w[7]);
        short8v av;
        __builtin_memcpy(&av, &au, 16);
        short8v bv = *(const short8v*)(hb + jb);
        acc = __builtin_amdgcn_mfma_f32_16x16x32_bf16(av, bv, acc, 0, 0, 0);
        accd = __builtin_amdgcn_mfma_f32_16x16x32_bf16(av, onesv, accd, 0, 0, 0);
    }

    #pragma unroll
    for (int reg = 0; reg < 4; ++reg) {
        int crow = g * 4 + reg;
        float dn = accd[reg];
        float v = dn > 0.f ? acc[reg] / dn : 0.f;
        v = v > 0.f ? v : expm1f(v);
        o2[((size_t)(b * N_NODES + t * 16 + crow)) * 48 + head * 16 + rs] = v;
    }
}

// ---------------- fc1 split-K with inline concat/projection staging ----------------
__global__ __launch_bounds__(256) void fc1_splitk_kernel(
    const float* __restrict__ x,
    const float* __restrict__ o1, const float* __restrict__ o2,
    const float* __restrict__ pw1, const float* __restrict__ pb1,
    const float* __restrict__ pw2, const float* __restrict__ pb2,
    const float* __restrict__ W, float* __restrict__ partial) {
    const int K = 6000, O = 600, KS = 71;
    __shared__ float sz[BS][KS];
    int tid = threadIdx.x;
    int kt = blockIdx.y;
    int k0 = kt * KS;
    int len = (k0 + KS <= K) ? KS : (K - k0);
    float pb1v = pb1[0], pb2v = pb2[0];
    for (int i = tid; i < BS * len; i += 256) {
        int bb = i / len, k = k0 + i % len;
        float v;
        if (k < 2000) {
            v = x[bb * 2000 + k];
        } else if (k < 4000) {
            const float* op = o1 + ((size_t)bb * 2000 + (k - 2000)) * 32;
            float s = pb1v;
            #pragma unroll
            for (int q = 0; q < 32; ++q) s = fmaf(op[q], pw1[q], s);
            v = s;
        } else {
            const float* op = o2 + ((size_t)bb * 2000 + (k - 4000)) * 48;
            float s = pb2v;
            #pragma unroll
            for (int q = 0; q < 48; ++q) s = fmaf(op[q], pw2[q], s);
            v = s;
        }
        sz[bb][i % len] = v;
    }
    __syncthreads();
    int o = blockIdx.x * 256 + tid;
    float acc[BS] = {0.f, 0.f, 0.f, 0.f, 0.f, 0.f, 0.f, 0.f};
    if (o < O) {
        for (int k = 0; k < len; ++k) {
            float w = W[(size_t)(k0 + k) * O + o];
            #pragma unroll
            for (int b = 0; b < BS; ++b) acc[b] = fmaf(sz[b][k], w, acc[b]);
        }
        #pragma unroll
        for (int b = 0; b < BS; ++b)
            partial[((size_t)kt * BS + b) * O + o] = acc[b];
    }
}

// ---------------- fc2 split-K with inline fc1-reduce staging — grid (1, 16) ----------
__global__ __launch_bounds__(256) void fc2_splitk_kernel(
    const float* __restrict__ p1, const float* __restrict__ b1,
    const float* __restrict__ W, float* __restrict__ partial) {
    const int K = 600, O = 256, KS = 38;
    __shared__ float sz[BS][KS];
    int tid = threadIdx.x;
    int kt = blockIdx.y;
    int k0 = kt * KS;
    int k1 = k0 + KS < K ? k0 + KS : K;
    int len = k1 - k0;
    for (int i = tid; i < BS * len; i += 256) {
        int bb = i / len, k = k0 + i % len;
        float a = b1[k];
        #pragma unroll 5
        for (int q = 0; q < 85; ++q) a += p1[((size_t)q * BS + bb) * 600 + k];
        sz[bb][i % len] = elu_f(a);
    }
    __syncthreads();
    int o = tid;
    float acc[BS] = {0.f, 0.f, 0.f, 0.f, 0.f, 0.f, 0.f, 0.f};
    for (int k = 0; k < len; ++k) {
        float w = W[(size_t)(k0 + k) * O + o];
        #pragma unroll
        for (int b = 0; b < BS; ++b) acc[b] = fmaf(sz[b][k], w, acc[b]);
    }
    #pragma unroll
    for (int b = 0; b < BS; ++b)
        partial[((size_t)kt * BS + b) * O + o] = acc[b];
}

// ---------------- fc_tail: p2-reduce + fc3 + fc4 + fc5 — grid (BS) ----------------
__global__ __launch_bounds__(256) void fc_tail_kernel(
    const float* __restrict__ p2, const float* __restrict__ b2,
    const float* __restrict__ w3, const float* __restrict__ b3,
    const float* __restrict__ w4, const float* __restrict__ b4,
    const float* __restrict__ w5, const float* __restrict__ b5,
    float* __restrict__ outp) {
    int b = blockIdx.x, tid = threadIdx.x;
    __shared__ float t2[256], red[256], z1[64], z4[32];
    {
        float a = b2[tid];
        #pragma unroll
        for (int kt = 0; kt < 16; ++kt) a += p2[((size_t)kt * BS + b) * 256 + tid];
        t2[tid] = elu_f(a);
    }
    __syncthreads();
    {
        int o = tid & 63, ks = tid >> 6;
        float a = 0.f;
        for (int k = ks; k < 256; k += 4) a = fmaf(t2[k], w3[k * 64 + o], a);
        red[tid] = a;
        __syncthreads();
        if (ks == 0) {
            float v = red[o] + red[64 + o] + red[128 + o] + red[192 + o] + b3[o];
            v = elu_f(v);
            z1[o] = v;
            outp[b * 64 + o] = v;
        }
    }
    __syncthreads();
    if (tid < 32) {
        float v = b4[tid];
        #pragma unroll
        for (int k = 0; k < 64; ++k) v = fmaf(z1[k], w4[k * 32 + tid], v);
        z4[tid] = elu_f(v);
    }
    __syncthreads();
    if (tid < 2) {
        float v = b5[tid];
        #pragma unroll
        for (int k = 0; k < 32; ++k) v = fmaf(z4[k], w5[k * 2 + tid], v);
        outp[BS * 64 + b * 2 + tid] = v;
    }
}

extern "C" void kernel_launch(void* const* d_in, const int* in_sizes, int n_in,
                              void* d_out, int out_size, void* d_ws, size_t ws_size,
                              hipStream_t stream) {
    const float* x    = (const float*)d_in[0];
    const float* adj  = (const float*)d_in[1];
    const float* W1   = (const float*)d_in[2];
    const float* a1   = (const float*)d_in[3];
    const float* W2   = (const float*)d_in[4];
    const float* a2   = (const float*)d_in[5];
    const float* pw1  = (const float*)d_in[6];
    const float* pb1  = (const float*)d_in[7];
    const float* pw2  = (const float*)d_in[8];
    const float* pb2  = (const float*)d_in[9];
    const float* fc1w = (const float*)d_in[10];
    const float* fc1b = (const float*)d_in[11];
    const float* fc2w = (const float*)d_in[12];
    const float* fc2b = (const float*)d_in[13];
    const float* fc3w = (const float*)d_in[14];
    const float* fc3b = (const float*)d_in[15];
    const float* fc4w = (const float*)d_in[16];
    const float* fc4b = (const float*)d_in[17];
    const float* fc5w = (const float*)d_in[18];
    const float* fc5b = (const float*)d_in[19];
    float* outp = (float*)d_out;

    float* ws = (float*)d_ws;
    size_t off = 0;
    auto alloc = [&](size_t n) {
        float* p = ws + off;
        off += (n + 63) & ~(size_t)63;
        return p;
    };
    float* o1   = alloc((size_t)BS * N_NODES * 32);
    float* s2   = alloc((size_t)24 * N_NODES);
    float* d2   = alloc((size_t)24 * N_NODES);
    short* hT   = (short*)alloc((size_t)24 * 16 * 2048 / 2);
    short* xb16 = (short*)alloc((size_t)BS * 2048 / 2);
    float* o2   = alloc((size_t)BS * N_NODES * 48);
    const int KT1 = 85;
    float* p1   = alloc((size_t)KT1 * BS * 600);
    float* p2   = alloc((size_t)16 * BS * 256);
    float* PQ1  = alloc((size_t)32 * 4096);
    float* md1  = alloc(64);
    unsigned* maskT32 = (unsigned*)alloc((size_t)64 * 2048);

    pack_kernel<<<N_NODES + 2 + 32, 256, 0, stream>>>(
        adj, x, W1, a1, maskT32, hT, xb16, PQ1, md1);
    att1_kernel<<<dim3(32, 4, BS), 256, 0, stream>>>(
        maskT32, x, xb16, PQ1, md1, W1, a1, o1);
    prep2_kernel<<<(BS * 3 * N_NODES + 255) / 256, 256, 0, stream>>>(o1, W2, a2, hT, s2, d2);
    att2_kernel<<<dim3(32, 3, BS), 256, 0, stream>>>(maskT32, hT, s2, d2, o2);
    fc1_splitk_kernel<<<dim3(3, KT1), 256, 0, stream>>>(
        x, o1, o2, pw1, pb1, pw2, pb2, fc1w, p1);
    fc2_splitk_kernel<<<dim3(1, 16), 256, 0, stream>>>(p1, fc1b, fc2w, p2);
    fc_tail_kernel<<<BS, 256, 0, stream>>>(
        p2, fc2b, fc3w, fc3b, fc4w, fc4b, fc5w, fc5b, outp);
}